// Round 1
// baseline (282.379 us; speedup 1.0000x reference)
//
#include <hip/hip_runtime.h>
#include <hip/hip_bf16.h>
#include <math.h>
#include <stdint.h>

typedef __bf16 bf16;
typedef __bf16 bf16x8 __attribute__((ext_vector_type(8)));
typedef __bf16 bf16x4v __attribute__((ext_vector_type(4)));
typedef float f32x4 __attribute__((ext_vector_type(4)));

#define NHEADS 4
#define DM 768
#define DB 64
#define HD 192
#define BATCH 8
#define SEQ 1024
#define MROWS 8192

__device__ __forceinline__ void gld_lds16(const void* g, void* l) {
  __builtin_amdgcn_global_load_lds(
      (__attribute__((address_space(1))) void*)(void*)g,
      (__attribute__((address_space(3))) void*)l, 16, 0, 0);
}

// ---------------- converts ----------------
__global__ __launch_bounds__(256) void cvt_f32_bf16(const float* __restrict__ in,
                                                    bf16* __restrict__ out, long n4) {
  long i = (long)blockIdx.x * blockDim.x + threadIdx.x;
  if (i >= n4) return;
  f32x4 v = *(const f32x4*)&in[i * 4];
  bf16x4v t;
  t[0] = (bf16)v[0]; t[1] = (bf16)v[1]; t[2] = (bf16)v[2]; t[3] = (bf16)v[3];
  *(bf16x4v*)&out[i * 4] = t;
}

__global__ __launch_bounds__(256) void transpose_bf16(const float* __restrict__ W,
                                                      bf16* __restrict__ WT, int K, int N) {
  long idx = (long)blockIdx.x * blockDim.x + threadIdx.x;
  if (idx >= (long)K * N) return;
  int k = (int)(idx % K);
  int n = (int)(idx / K);
  WT[(long)n * K + k] = (bf16)W[(long)k * N + n];
}

// ---------------- bias MLP ----------------
__global__ __launch_bounds__(256) void bias_mlp(const float* __restrict__ bloom,
                                                const float* __restrict__ Wb1,
                                                const float* __restrict__ bb1,
                                                const float* __restrict__ Wb2,
                                                const float* __restrict__ bb2,
                                                float* __restrict__ biasarr) {
  int idx = blockIdx.x * blockDim.x + threadIdx.x;
  if (idx >= MROWS) return;
  const float* x = bloom + (long)idx * DB;
  float h[8];
#pragma unroll
  for (int j = 0; j < 8; ++j) h[j] = bb1[j];
  for (int k = 0; k < DB; ++k) {
    float xv = x[k];
#pragma unroll
    for (int j = 0; j < 8; ++j) h[j] = fmaf(xv, Wb1[k * 8 + j], h[j]);
  }
#pragma unroll
  for (int j = 0; j < 8; ++j) {
    float a = h[j];
    h[j] = 0.5f * a * (1.0f + erff(a * 0.7071067811865476f));
  }
  int b = idx >> 10, s = idx & 1023;
#pragma unroll
  for (int o = 0; o < 4; ++o) {
    float a = bb2[o];
#pragma unroll
    for (int j = 0; j < 8; ++j) a = fmaf(h[j], Wb2[j * 4 + o], a);
    biasarr[((long)(b * 4 + o) << 10) + s] = a;
  }
}

// ---------------- GEMM (A row-major [M,K] bf16, BT row-major [N,K] bf16) ----------------
// MODE 0: bf16 out, ld=DM, +colbias             (Q,K projections)
// MODE 1: bf16 out transposed per batch -> VT   (V projection)
// MODE 2: f32 out = acc*scale + biasarr, batched per (b,h)  (scores)
// MODE 3: A is f32 (attn), out bf16 ctx at col offset h*HD  (PV)
// MODE 4: f32 out = acc + colbias + resid        (final x)
template <int MODE>
__global__ __launch_bounds__(256) void gemm_bt(
    const bf16* __restrict__ A, int lda,
    const bf16* __restrict__ BT, int ldb,
    const float* __restrict__ Af,
    int M, int N, int Kd,
    const float* __restrict__ colbias,
    const float* __restrict__ biasarr,
    const float* __restrict__ resid,
    void* __restrict__ out) {
  __shared__ __attribute__((aligned(16))) bf16 aL[128 * 32];
  __shared__ __attribute__((aligned(16))) bf16 bL[128 * 32];
  const int tid = threadIdx.x;
  const int lane = tid & 63;
  const int wid = tid >> 6;
  const int wr = wid >> 1, wc = wid & 1;
  const int m0 = blockIdx.y * 128, n0 = blockIdx.x * 128;
  const int z = blockIdx.z;

  long aoff = 0, boff = 0;
  if (MODE == 2) {
    int b = z >> 2, h = z & 3;
    aoff = ((long)b * SEQ) * DM + (long)h * HD;
    boff = aoff;
  }
  if (MODE == 3) {
    int b = z >> 2, h = z & 3;
    boff = ((long)(b * DM + h * HD)) << 10;
  }
  const bf16* Ab = A + aoff;
  const bf16* Bb = BT + boff;
  const float* Afb = (MODE == 3) ? (Af + ((long)z << 20)) : nullptr;

  f32x4 acc[4][4] = {};

  for (int k0 = 0; k0 < Kd; k0 += 32) {
    if constexpr (MODE == 3) {
#pragma unroll
      for (int p = 0; p < 2; ++p) {
        int f = (p * 256 + tid) * 8;
        int row = f >> 5, col = f & 31;
        const float* g = Afb + (long)(m0 + row) * lda + k0 + col;
        f32x4 x0 = *(const f32x4*)g;
        f32x4 x1 = *(const f32x4*)(g + 4);
        bf16x8 t;
        t[0] = (bf16)x0[0]; t[1] = (bf16)x0[1]; t[2] = (bf16)x0[2]; t[3] = (bf16)x0[3];
        t[4] = (bf16)x1[0]; t[5] = (bf16)x1[1]; t[6] = (bf16)x1[2]; t[7] = (bf16)x1[3];
        *(bf16x8*)&aL[f] = t;
      }
    } else {
#pragma unroll
      for (int p = 0; p < 2; ++p) {
        int f = (p * 256 + tid) * 8;
        int row = f >> 5, col = f & 31;
        gld_lds16(Ab + (long)(m0 + row) * lda + k0 + col, &aL[f]);
      }
    }
#pragma unroll
    for (int p = 0; p < 2; ++p) {
      int f = (p * 256 + tid) * 8;
      int row = f >> 5, col = f & 31;
      int nn = n0 + row;
      nn = nn < N ? nn : N - 1;
      gld_lds16(Bb + (long)nn * ldb + k0 + col, &bL[f]);
    }
    __syncthreads();

    const int rsel = lane & 15, ksel = (lane >> 4) * 8;
    bf16x8 af[4], bfr[4];
#pragma unroll
    for (int m = 0; m < 4; ++m)
      af[m] = *(const bf16x8*)&aL[(wr * 64 + m * 16 + rsel) * 32 + ksel];
#pragma unroll
    for (int n = 0; n < 4; ++n)
      bfr[n] = *(const bf16x8*)&bL[(wc * 64 + n * 16 + rsel) * 32 + ksel];
#pragma unroll
    for (int m = 0; m < 4; ++m)
#pragma unroll
      for (int n = 0; n < 4; ++n)
        acc[m][n] = __builtin_amdgcn_mfma_f32_16x16x32_bf16(af[m], bfr[n], acc[m][n], 0, 0, 0);
    __syncthreads();
  }

  const int rl = (lane >> 4) * 4, cl = lane & 15;
#pragma unroll
  for (int m = 0; m < 4; ++m) {
#pragma unroll
    for (int n = 0; n < 4; ++n) {
      int ng = n0 + wc * 64 + n * 16 + cl;
      if (ng >= N) continue;
#pragma unroll
      for (int j = 0; j < 4; ++j) {
        int mg = m0 + wr * 64 + m * 16 + rl + j;
        float v = acc[m][n][j];
        if constexpr (MODE == 0) {
          ((bf16*)out)[(long)mg * DM + ng] = (bf16)(v + colbias[ng]);
        } else if constexpr (MODE == 1) {
          int b = mg >> 10, s = mg & 1023;
          ((bf16*)out)[((long)(b * DM + ng) << 10) + s] = (bf16)(v + colbias[ng]);
        } else if constexpr (MODE == 2) {
          ((float*)out)[((long)z << 20) + ((long)mg << 10) + ng] =
              v * 0.07216878364870323f + biasarr[(z << 10) + ng];
        } else if constexpr (MODE == 3) {
          int b = z >> 2, h = z & 3;
          ((bf16*)out)[(long)(b * SEQ + mg) * DM + h * HD + ng] = (bf16)v;
        } else {
          long o = (long)mg * DM + ng;
          ((float*)out)[o] = v + colbias[ng] + resid[o];
        }
      }
    }
  }
}

// ---------------- softmax (one wave per row of 1024) ----------------
__global__ __launch_bounds__(256) void softmax_rows(float* attn) {
  int row = blockIdx.x * 4 + (threadIdx.x >> 6);
  int lane = threadIdx.x & 63;
  float* r = attn + ((long)row << 10);
  f32x4 v[4];
#pragma unroll
  for (int i = 0; i < 4; ++i) v[i] = *(const f32x4*)&r[i * 256 + lane * 4];
  float mx = -1e30f;
#pragma unroll
  for (int i = 0; i < 4; ++i)
#pragma unroll
    for (int j = 0; j < 4; ++j) mx = fmaxf(mx, v[i][j]);
  for (int d = 1; d < 64; d <<= 1) mx = fmaxf(mx, __shfl_xor(mx, d));
  float sum = 0.0f;
#pragma unroll
  for (int i = 0; i < 4; ++i)
#pragma unroll
    for (int j = 0; j < 4; ++j) {
      v[i][j] = expf(v[i][j] - mx);
      sum += v[i][j];
    }
  for (int d = 1; d < 64; d <<= 1) sum += __shfl_xor(sum, d);
  float inv = 1.0f / sum;
#pragma unroll
  for (int i = 0; i < 4; ++i) {
#pragma unroll
    for (int j = 0; j < 4; ++j) v[i][j] *= inv;
    *(f32x4*)&r[i * 256 + lane * 4] = v[i];
  }
}

// ---------------- layernorm (one wave per row of 768, in place) ----------------
__global__ __launch_bounds__(256) void layernorm_rows(float* x, const float* __restrict__ gam,
                                                      const float* __restrict__ bet) {
  int row = blockIdx.x * 4 + (threadIdx.x >> 6);
  int lane = threadIdx.x & 63;
  float* r = x + (long)row * DM;
  f32x4 v[3];
#pragma unroll
  for (int i = 0; i < 3; ++i) v[i] = *(const f32x4*)&r[i * 256 + lane * 4];
  float s = 0.0f, ss = 0.0f;
#pragma unroll
  for (int i = 0; i < 3; ++i)
#pragma unroll
    for (int j = 0; j < 4; ++j) {
      s += v[i][j];
      ss += v[i][j] * v[i][j];
    }
  for (int d = 1; d < 64; d <<= 1) {
    s += __shfl_xor(s, d);
    ss += __shfl_xor(ss, d);
  }
  float mu = s * (1.0f / 768.0f);
  float var = ss * (1.0f / 768.0f) - mu * mu;
  float rs = 1.0f / sqrtf(var + 1e-5f);
#pragma unroll
  for (int i = 0; i < 3; ++i) {
#pragma unroll
    for (int j = 0; j < 4; ++j) {
      int c = i * 256 + lane * 4 + j;
      v[i][j] = (v[i][j] - mu) * rs * gam[c] + bet[c];
    }
    *(f32x4*)&r[i * 256 + lane * 4] = v[i];
  }
}

// ---------------- launcher ----------------
extern "C" void kernel_launch(void* const* d_in, const int* in_sizes, int n_in,
                              void* d_out, int out_size, void* d_ws, size_t ws_size,
                              hipStream_t stream) {
  const float* Xd = (const float*)d_in[0];
  const float* Xb = (const float*)d_in[1];
  const float* Wq = (const float*)d_in[2];
  const float* bq = (const float*)d_in[3];
  const float* Wk = (const float*)d_in[4];
  const float* bk = (const float*)d_in[5];
  const float* Wv = (const float*)d_in[6];
  const float* bv = (const float*)d_in[7];
  const float* Wb1 = (const float*)d_in[8];
  const float* bb1 = (const float*)d_in[9];
  const float* Wb2 = (const float*)d_in[10];
  const float* bb2 = (const float*)d_in[11];
  const float* Wo = (const float*)d_in[12];
  const float* bo = (const float*)d_in[13];
  const float* lng = (const float*)d_in[14];
  const float* lnb = (const float*)d_in[15];

  float* y = (float*)d_out;                  // 8192*768 f32
  float* attn = y + (long)MROWS * DM;        // 32*1024*1024 f32

  char* w = (char*)d_ws;
  bf16* Xd_bf = (bf16*)w; w += (long)MROWS * DM * 2;
  bf16* Xb_bf = (bf16*)w; w += (long)MROWS * DB * 2;
  bf16* WqT = (bf16*)w; w += (long)DM * DM * 2;
  bf16* WkT = (bf16*)w; w += (long)DM * DB * 2;
  bf16* WvT = (bf16*)w; w += (long)DM * DM * 2;
  bf16* WoT = (bf16*)w; w += (long)DM * DM * 2;
  bf16* Qb = (bf16*)w; w += (long)MROWS * DM * 2;
  bf16* Kb = (bf16*)w; w += (long)MROWS * DM * 2;
  bf16* VTb = (bf16*)w; w += (long)MROWS * DM * 2;
  bf16* ctxb = (bf16*)w; w += (long)MROWS * DM * 2;
  float* biasarr = (float*)w; w += (long)BATCH * NHEADS * SEQ * 4;

  cvt_f32_bf16<<<6144, 256, 0, stream>>>(Xd, Xd_bf, (long)MROWS * DM / 4);
  cvt_f32_bf16<<<512, 256, 0, stream>>>(Xb, Xb_bf, (long)MROWS * DB / 4);
  transpose_bf16<<<2304, 256, 0, stream>>>(Wq, WqT, DM, DM);
  transpose_bf16<<<192, 256, 0, stream>>>(Wk, WkT, DB, DM);
  transpose_bf16<<<2304, 256, 0, stream>>>(Wv, WvT, DM, DM);
  transpose_bf16<<<2304, 256, 0, stream>>>(Wo, WoT, DM, DM);
  bias_mlp<<<32, 256, 0, stream>>>(Xb, Wb1, bb1, Wb2, bb2, biasarr);

  dim3 blk(256);
  // Q = Xd @ Wq + bq
  gemm_bt<0><<<dim3(6, 64, 1), blk, 0, stream>>>(Xd_bf, DM, WqT, DM, nullptr, MROWS, DM, DM,
                                                 bq, nullptr, nullptr, Qb);
  // K = Xb @ Wk + bk
  gemm_bt<0><<<dim3(6, 64, 1), blk, 0, stream>>>(Xb_bf, DB, WkT, DB, nullptr, MROWS, DM, DB,
                                                 bk, nullptr, nullptr, Kb);
  // V = Xd @ Wv + bv  (stored transposed per batch)
  gemm_bt<1><<<dim3(6, 64, 1), blk, 0, stream>>>(Xd_bf, DM, WvT, DM, nullptr, MROWS, DM, DM,
                                                 bv, nullptr, nullptr, VTb);
  // scores = Q K^T / sqrt(Dh) + bias  -> f32 attn buffer
  gemm_bt<2><<<dim3(8, 8, 32), blk, 0, stream>>>(Qb, DM, Kb, DM, nullptr, SEQ, SEQ, HD,
                                                 nullptr, biasarr, nullptr, attn);
  softmax_rows<<<8192, 256, 0, stream>>>(attn);
  // ctx = attn @ V
  gemm_bt<3><<<dim3(2, 8, 32), blk, 0, stream>>>(nullptr, SEQ, VTb, SEQ, attn, SEQ, HD, SEQ,
                                                 nullptr, nullptr, nullptr, ctxb);
  // x = ctx @ Wo + bo + resid -> y region
  gemm_bt<4><<<dim3(6, 64, 1), blk, 0, stream>>>(ctxb, DM, WoT, DM, nullptr, MROWS, DM, DM,
                                                 bo, nullptr, Xd, y);
  layernorm_rows<<<2048, 256, 0, stream>>>(y, lng, lnb);
}

// Round 2
// 251.784 us; speedup vs baseline: 1.1215x; 1.1215x over previous
//
#include <hip/hip_runtime.h>
#include <hip/hip_bf16.h>
#include <math.h>
#include <stdint.h>

typedef __bf16 bf16;
typedef __bf16 bf16x8 __attribute__((ext_vector_type(8)));
typedef __bf16 bf16x4v __attribute__((ext_vector_type(4)));
typedef float f32x4 __attribute__((ext_vector_type(4)));

#define NHEADS 4
#define DM 768
#define DB 64
#define HD 192
#define BATCH 8
#define SEQ 1024
#define MROWS 8192

__device__ __forceinline__ void gld_lds16(const void* g, void* l) {
  __builtin_amdgcn_global_load_lds(
      (__attribute__((address_space(1))) void*)(void*)g,
      (__attribute__((address_space(3))) void*)l, 16, 0, 0);
}

// ---------------- converts ----------------
__global__ __launch_bounds__(256) void cvt_f32_bf16(const float* __restrict__ in,
                                                    bf16* __restrict__ out, long n4) {
  long i = (long)blockIdx.x * blockDim.x + threadIdx.x;
  if (i >= n4) return;
  f32x4 v = *(const f32x4*)&in[i * 4];
  bf16x4v t;
  t[0] = (bf16)v[0]; t[1] = (bf16)v[1]; t[2] = (bf16)v[2]; t[3] = (bf16)v[3];
  *(bf16x4v*)&out[i * 4] = t;
}

__global__ __launch_bounds__(256) void transpose_bf16(const float* __restrict__ W,
                                                      bf16* __restrict__ WT, int K, int N) {
  long idx = (long)blockIdx.x * blockDim.x + threadIdx.x;
  if (idx >= (long)K * N) return;
  int k = (int)(idx % K);
  int n = (int)(idx / K);
  WT[(long)n * K + k] = (bf16)W[(long)k * N + n];
}

// ---------------- bias MLP ----------------
__global__ __launch_bounds__(256) void bias_mlp(const float* __restrict__ bloom,
                                                const float* __restrict__ Wb1,
                                                const float* __restrict__ bb1,
                                                const float* __restrict__ Wb2,
                                                const float* __restrict__ bb2,
                                                float* __restrict__ biasarr) {
  int idx = blockIdx.x * blockDim.x + threadIdx.x;
  if (idx >= MROWS) return;
  const float* x = bloom + (long)idx * DB;
  float h[8];
#pragma unroll
  for (int j = 0; j < 8; ++j) h[j] = bb1[j];
  for (int k = 0; k < DB; ++k) {
    float xv = x[k];
#pragma unroll
    for (int j = 0; j < 8; ++j) h[j] = fmaf(xv, Wb1[k * 8 + j], h[j]);
  }
#pragma unroll
  for (int j = 0; j < 8; ++j) {
    float a = h[j];
    h[j] = 0.5f * a * (1.0f + erff(a * 0.7071067811865476f));
  }
  int b = idx >> 10, s = idx & 1023;
#pragma unroll
  for (int o = 0; o < 4; ++o) {
    float a = bb2[o];
#pragma unroll
    for (int j = 0; j < 8; ++j) a = fmaf(h[j], Wb2[j * 4 + o], a);
    biasarr[((long)(b * 4 + o) << 10) + s] = a;
  }
}

// ---------------- fused scores + bias + softmax ----------------
// grid: 512 1-D blocks, 512 threads. id: z = id&31 (b*4+h), rb = id>>5 (row block of 64).
// Each of 8 waves owns a 128-col slice of the full 1024-key row.
// Writes normalized attn (f32, d_out) and optionally bf16 P for the PV gemm.
template <bool WRITE_P>
__global__ __launch_bounds__(512) void scores_softmax(
    const bf16* __restrict__ Qb, const bf16* __restrict__ Kb,
    const float* __restrict__ biasarr, float* __restrict__ attn,
    bf16* __restrict__ P) {
  __shared__ __attribute__((aligned(16))) bf16 bL[1024 * 32];  // 64 KB
  const int tid = threadIdx.x;
  const int lane = tid & 63;
  const int wid = tid >> 6;  // 0..7 -> col slice
  const int id = blockIdx.x;
  const int z = id & 31;      // same-z blocks share an XCD (id%8 == z%8)
  const int m0 = (id >> 5) * 64;
  const int b = z >> 2, h = z & 3;
  const bf16* Qbase = Qb + ((long)(b * SEQ + m0)) * DM + h * HD;
  const bf16* Kbase = Kb + ((long)(b * SEQ)) * DM + h * HD;
  const int rsel = lane & 15, ksel = (lane >> 4) * 8;
  const int rl = (lane >> 4) * 4;

  f32x4 acc[4][8] = {};

  for (int k0 = 0; k0 < HD; k0 += 32) {
#pragma unroll
    for (int p = 0; p < 8; ++p) {
      int f = (p * 512 + tid) * 8;
      int row = f >> 5, col = f & 31;
      gld_lds16(Kbase + (long)row * DM + k0 + col, &bL[f]);
    }
    bf16x8 af[4];
#pragma unroll
    for (int m = 0; m < 4; ++m)
      af[m] = *(const bf16x8*)(Qbase + (long)(m * 16 + rsel) * DM + k0 + ksel);
    __syncthreads();
    bf16x8 bfr[8];
#pragma unroll
    for (int n = 0; n < 8; ++n)
      bfr[n] = *(const bf16x8*)&bL[(wid * 128 + n * 16 + rsel) * 32 + ksel];
#pragma unroll
    for (int m = 0; m < 4; ++m)
#pragma unroll
      for (int n = 0; n < 8; ++n)
        acc[m][n] = __builtin_amdgcn_mfma_f32_16x16x32_bf16(af[m], bfr[n], acc[m][n], 0, 0, 0);
    __syncthreads();
  }

  // epilogue: scale + bias, row softmax across 1024 keys
  float* red = (float*)bL;  // staging dead; reuse as [8][64] partials
  const float scale = 0.07216878364870323f;
  float bv[8];
#pragma unroll
  for (int n = 0; n < 8; ++n)
    bv[n] = biasarr[(z << 10) + wid * 128 + n * 16 + rsel];

  float pm[4][4];
#pragma unroll
  for (int m = 0; m < 4; ++m)
#pragma unroll
    for (int j = 0; j < 4; ++j) {
      float mx = -1e30f;
#pragma unroll
      for (int n = 0; n < 8; ++n) {
        acc[m][n][j] = fmaf(acc[m][n][j], scale, bv[n]);
        mx = fmaxf(mx, acc[m][n][j]);
      }
      pm[m][j] = mx;
    }
#pragma unroll
  for (int d = 1; d < 16; d <<= 1)
#pragma unroll
    for (int m = 0; m < 4; ++m)
#pragma unroll
      for (int j = 0; j < 4; ++j)
        pm[m][j] = fmaxf(pm[m][j], __shfl_xor(pm[m][j], d));
  if (rsel == 0) {
#pragma unroll
    for (int m = 0; m < 4; ++m)
#pragma unroll
      for (int j = 0; j < 4; ++j)
        red[wid * 64 + m * 16 + rl + j] = pm[m][j];
  }
  __syncthreads();
  float rmax[4][4];
#pragma unroll
  for (int m = 0; m < 4; ++m)
#pragma unroll
    for (int j = 0; j < 4; ++j) {
      float mx = -1e30f;
#pragma unroll
      for (int w = 0; w < 8; ++w)
        mx = fmaxf(mx, red[w * 64 + m * 16 + rl + j]);
      rmax[m][j] = mx;
    }
  __syncthreads();

  float ps[4][4];
#pragma unroll
  for (int m = 0; m < 4; ++m)
#pragma unroll
    for (int j = 0; j < 4; ++j) {
      float s = 0.0f;
#pragma unroll
      for (int n = 0; n < 8; ++n) {
        float e = __expf(acc[m][n][j] - rmax[m][j]);
        acc[m][n][j] = e;
        s += e;
      }
      ps[m][j] = s;
    }
#pragma unroll
  for (int d = 1; d < 16; d <<= 1)
#pragma unroll
    for (int m = 0; m < 4; ++m)
#pragma unroll
      for (int j = 0; j < 4; ++j)
        ps[m][j] += __shfl_xor(ps[m][j], d);
  if (rsel == 0) {
#pragma unroll
    for (int m = 0; m < 4; ++m)
#pragma unroll
      for (int j = 0; j < 4; ++j)
        red[wid * 64 + m * 16 + rl + j] = ps[m][j];
  }
  __syncthreads();

  long obase = ((long)z << 20) + ((long)m0 << 10) + wid * 128;
#pragma unroll
  for (int m = 0; m < 4; ++m)
#pragma unroll
    for (int j = 0; j < 4; ++j) {
      float tot = 0.0f;
#pragma unroll
      for (int w = 0; w < 8; ++w) tot += red[w * 64 + m * 16 + rl + j];
      float inv = 1.0f / tot;
      long rb = obase + ((long)(m * 16 + rl + j) << 10);
#pragma unroll
      for (int n = 0; n < 8; ++n) {
        float v = acc[m][n][j] * inv;
        attn[rb + n * 16 + rsel] = v;
        if constexpr (WRITE_P) P[rb + n * 16 + rsel] = (bf16)v;
      }
    }
}

// ---------------- GEMM (A row-major [M,K] bf16, BT row-major [N,K] bf16) ----------------
// MODE 0: bf16 out, ld=DM, +colbias             (Q,K projections)
// MODE 1: bf16 out transposed per batch -> VT   (V projection)
// MODE 3: A bf16 batched (P), out bf16 ctx at col offset h*HD (PV, fast path)
// MODE 4: f32 out = acc + colbias + resid       (final x)
// MODE 5: A f32 batched (attn), out like MODE 3 (PV, fallback path)
template <int MODE>
__global__ __launch_bounds__(256) void gemm_bt(
    const bf16* __restrict__ A, int lda,
    const bf16* __restrict__ BT, int ldb,
    const float* __restrict__ Af,
    int M, int N, int Kd,
    const float* __restrict__ colbias,
    const float* __restrict__ resid,
    void* __restrict__ out) {
  __shared__ __attribute__((aligned(16))) bf16 aL[128 * 32];
  __shared__ __attribute__((aligned(16))) bf16 bL[128 * 32];
  const int tid = threadIdx.x;
  const int lane = tid & 63;
  const int wid = tid >> 6;
  const int wr = wid >> 1, wc = wid & 1;
  int bx, by, bz;
  if constexpr (MODE == 3 || MODE == 5) {
    int idd = blockIdx.x;          // 512 blocks: z=idd&31 keeps (b,h) on one XCD
    bz = idd & 31;
    bx = (idd >> 5) & 1;
    by = idd >> 6;
  } else {
    bx = blockIdx.x; by = blockIdx.y; bz = blockIdx.z;
  }
  const int m0 = by * 128, n0 = bx * 128;
  const int z = bz;

  long aoff = 0, boff = 0;
  if (MODE == 3 || MODE == 5) {
    int b = z >> 2, h = z & 3;
    aoff = (long)z << 20;
    boff = ((long)(b * DM + h * HD)) << 10;
  }
  const bf16* Ab = A + aoff;
  const bf16* Bb = BT + boff;
  const float* Afb = (MODE == 5) ? (Af + ((long)z << 20)) : nullptr;

  f32x4 acc[4][4] = {};

  for (int k0 = 0; k0 < Kd; k0 += 32) {
    if constexpr (MODE == 5) {
#pragma unroll
      for (int p = 0; p < 2; ++p) {
        int f = (p * 256 + tid) * 8;
        int row = f >> 5, col = f & 31;
        const float* g = Afb + (long)(m0 + row) * lda + k0 + col;
        f32x4 x0 = *(const f32x4*)g;
        f32x4 x1 = *(const f32x4*)(g + 4);
        bf16x8 t;
        t[0] = (bf16)x0[0]; t[1] = (bf16)x0[1]; t[2] = (bf16)x0[2]; t[3] = (bf16)x0[3];
        t[4] = (bf16)x1[0]; t[5] = (bf16)x1[1]; t[6] = (bf16)x1[2]; t[7] = (bf16)x1[3];
        *(bf16x8*)&aL[f] = t;
      }
    } else {
#pragma unroll
      for (int p = 0; p < 2; ++p) {
        int f = (p * 256 + tid) * 8;
        int row = f >> 5, col = f & 31;
        gld_lds16(Ab + (long)(m0 + row) * lda + k0 + col, &aL[f]);
      }
    }
#pragma unroll
    for (int p = 0; p < 2; ++p) {
      int f = (p * 256 + tid) * 8;
      int row = f >> 5, col = f & 31;
      int nn = n0 + row;
      nn = nn < N ? nn : N - 1;
      gld_lds16(Bb + (long)nn * ldb + k0 + col, &bL[f]);
    }
    __syncthreads();

    const int rsel = lane & 15, ksel = (lane >> 4) * 8;
    bf16x8 af[4], bfr[4];
#pragma unroll
    for (int m = 0; m < 4; ++m)
      af[m] = *(const bf16x8*)&aL[(wr * 64 + m * 16 + rsel) * 32 + ksel];
#pragma unroll
    for (int n = 0; n < 4; ++n)
      bfr[n] = *(const bf16x8*)&bL[(wc * 64 + n * 16 + rsel) * 32 + ksel];
#pragma unroll
    for (int m = 0; m < 4; ++m)
#pragma unroll
      for (int n = 0; n < 4; ++n)
        acc[m][n] = __builtin_amdgcn_mfma_f32_16x16x32_bf16(af[m], bfr[n], acc[m][n], 0, 0, 0);
    __syncthreads();
  }

  const int rl = (lane >> 4) * 4, cl = lane & 15;
#pragma unroll
  for (int m = 0; m < 4; ++m) {
#pragma unroll
    for (int n = 0; n < 4; ++n) {
      int ng = n0 + wc * 64 + n * 16 + cl;
      if (ng >= N) continue;
#pragma unroll
      for (int j = 0; j < 4; ++j) {
        int mg = m0 + wr * 64 + m * 16 + rl + j;
        float v = acc[m][n][j];
        if constexpr (MODE == 0) {
          ((bf16*)out)[(long)mg * DM + ng] = (bf16)(v + colbias[ng]);
        } else if constexpr (MODE == 1) {
          int b = mg >> 10, s = mg & 1023;
          ((bf16*)out)[((long)(b * DM + ng) << 10) + s] = (bf16)(v + colbias[ng]);
        } else if constexpr (MODE == 3 || MODE == 5) {
          int b = z >> 2, h = z & 3;
          ((bf16*)out)[(long)(b * SEQ + mg) * DM + h * HD + ng] = (bf16)v;
        } else {
          long o = (long)mg * DM + ng;
          ((float*)out)[o] = v + colbias[ng] + resid[o];
        }
      }
    }
  }
}

// ---------------- layernorm (one wave per row of 768, in place) ----------------
__global__ __launch_bounds__(256) void layernorm_rows(float* x, const float* __restrict__ gam,
                                                      const float* __restrict__ bet) {
  int row = blockIdx.x * 4 + (threadIdx.x >> 6);
  int lane = threadIdx.x & 63;
  float* r = x + (long)row * DM;
  f32x4 v[3];
#pragma unroll
  for (int i = 0; i < 3; ++i) v[i] = *(const f32x4*)&r[i * 256 + lane * 4];
  float s = 0.0f, ss = 0.0f;
#pragma unroll
  for (int i = 0; i < 3; ++i)
#pragma unroll
    for (int j = 0; j < 4; ++j) {
      s += v[i][j];
      ss += v[i][j] * v[i][j];
    }
  for (int d = 1; d < 64; d <<= 1) {
    s += __shfl_xor(s, d);
    ss += __shfl_xor(ss, d);
  }
  float mu = s * (1.0f / 768.0f);
  float var = ss * (1.0f / 768.0f) - mu * mu;
  float rs = 1.0f / sqrtf(var + 1e-5f);
#pragma unroll
  for (int i = 0; i < 3; ++i) {
#pragma unroll
    for (int j = 0; j < 4; ++j) {
      int c = i * 256 + lane * 4 + j;
      v[i][j] = (v[i][j] - mu) * rs * gam[c] + bet[c];
    }
    *(f32x4*)&r[i * 256 + lane * 4] = v[i];
  }
}

// ---------------- launcher ----------------
extern "C" void kernel_launch(void* const* d_in, const int* in_sizes, int n_in,
                              void* d_out, int out_size, void* d_ws, size_t ws_size,
                              hipStream_t stream) {
  const float* Xd = (const float*)d_in[0];
  const float* Xb = (const float*)d_in[1];
  const float* Wq = (const float*)d_in[2];
  const float* bq = (const float*)d_in[3];
  const float* Wk = (const float*)d_in[4];
  const float* bk = (const float*)d_in[5];
  const float* Wv = (const float*)d_in[6];
  const float* bv = (const float*)d_in[7];
  const float* Wb1 = (const float*)d_in[8];
  const float* bb1 = (const float*)d_in[9];
  const float* Wb2 = (const float*)d_in[10];
  const float* bb2 = (const float*)d_in[11];
  const float* Wo = (const float*)d_in[12];
  const float* bo = (const float*)d_in[13];
  const float* lng = (const float*)d_in[14];
  const float* lnb = (const float*)d_in[15];

  float* y = (float*)d_out;                  // 8192*768 f32
  float* attn = y + (long)MROWS * DM;        // 32*1024*1024 f32

  char* w = (char*)d_ws;
  bf16* Xd_bf = (bf16*)w; w += (long)MROWS * DM * 2;
  bf16* Xb_bf = (bf16*)w; w += (long)MROWS * DB * 2;
  bf16* WqT = (bf16*)w; w += (long)DM * DM * 2;
  bf16* WkT = (bf16*)w; w += (long)DM * DB * 2;
  bf16* WvT = (bf16*)w; w += (long)DM * DM * 2;
  bf16* WoT = (bf16*)w; w += (long)DM * DM * 2;
  bf16* Qb = (bf16*)w; w += (long)MROWS * DM * 2;
  bf16* Kb = (bf16*)w; w += (long)MROWS * DM * 2;
  bf16* VTb = (bf16*)w; w += (long)MROWS * DM * 2;
  bf16* ctxb = (bf16*)w; w += (long)MROWS * DM * 2;
  float* biasarr = (float*)w; w += (long)BATCH * NHEADS * SEQ * 4;
  bf16* Pb = (bf16*)w; w += (long)32 * SEQ * SEQ * 2;   // 64 MB, optional
  const bool useP = ((size_t)(w - (char*)d_ws)) <= ws_size;

  cvt_f32_bf16<<<6144, 256, 0, stream>>>(Xd, Xd_bf, (long)MROWS * DM / 4);
  cvt_f32_bf16<<<512, 256, 0, stream>>>(Xb, Xb_bf, (long)MROWS * DB / 4);
  transpose_bf16<<<2304, 256, 0, stream>>>(Wq, WqT, DM, DM);
  transpose_bf16<<<192, 256, 0, stream>>>(Wk, WkT, DB, DM);
  transpose_bf16<<<2304, 256, 0, stream>>>(Wv, WvT, DM, DM);
  transpose_bf16<<<2304, 256, 0, stream>>>(Wo, WoT, DM, DM);
  bias_mlp<<<32, 256, 0, stream>>>(Xb, Wb1, bb1, Wb2, bb2, biasarr);

  dim3 blk(256);
  // Q = Xd @ Wq + bq
  gemm_bt<0><<<dim3(6, 64, 1), blk, 0, stream>>>(Xd_bf, DM, WqT, DM, nullptr, MROWS, DM, DM,
                                                 bq, nullptr, Qb);
  // K = Xb @ Wk + bk
  gemm_bt<0><<<dim3(6, 64, 1), blk, 0, stream>>>(Xb_bf, DB, WkT, DB, nullptr, MROWS, DM, DB,
                                                 bk, nullptr, Kb);
  // V = Xd @ Wv + bv  (stored transposed per batch)
  gemm_bt<1><<<dim3(6, 64, 1), blk, 0, stream>>>(Xd_bf, DM, WvT, DM, nullptr, MROWS, DM, DM,
                                                 bv, nullptr, VTb);
  // scores + bias + softmax fused -> attn f32 (+ P bf16)
  if (useP) {
    scores_softmax<true><<<512, 512, 0, stream>>>(Qb, Kb, biasarr, attn, Pb);
    gemm_bt<3><<<512, blk, 0, stream>>>(Pb, SEQ, VTb, SEQ, nullptr, SEQ, HD, SEQ,
                                        nullptr, nullptr, ctxb);
  } else {
    scores_softmax<false><<<512, 512, 0, stream>>>(Qb, Kb, biasarr, attn, nullptr);
    gemm_bt<5><<<512, blk, 0, stream>>>(nullptr, SEQ, VTb, SEQ, attn, SEQ, HD, SEQ,
                                        nullptr, nullptr, ctxb);
  }
  // x = ctx @ Wo + bo + resid -> y region
  gemm_bt<4><<<dim3(6, 64, 1), blk, 0, stream>>>(ctxb, DM, WoT, DM, nullptr, MROWS, DM, DM,
                                                 bo, Xd, y);
  layernorm_rows<<<2048, 256, 0, stream>>>(y, lng, lnb);
}